// Round 1
// baseline (605.166 us; speedup 1.0000x reference)
//
#include <hip/hip_runtime.h>

typedef __attribute__((ext_vector_type(8))) short short8;
typedef __attribute__((ext_vector_type(4))) unsigned short ushort4v;
typedef __attribute__((ext_vector_type(4))) float f32x4;

__device__ __forceinline__ float b2f(unsigned short u) {
    unsigned int i = ((unsigned int)u) << 16;
    return __builtin_bit_cast(float, i);
}
__device__ __forceinline__ unsigned short f2b(float f) {
    unsigned int u = __builtin_bit_cast(unsigned int, f);
    unsigned int r = (u + 0x7fffu + ((u >> 16) & 1u)) >> 16;
    return (unsigned short)r;
}

// async 16B global->LDS copy; lds base must be wave-uniform (HW adds lane*16B)
__device__ __forceinline__ void async16(unsigned short* lds, const unsigned short* g) {
    __builtin_amdgcn_global_load_lds(
        (const __attribute__((address_space(1))) unsigned int*)g,
        (__attribute__((address_space(3))) unsigned int*)lds,
        16, 0, 0);
}

// XCD-aware block swizzle (gridDim.y % 8 == 0 required; pure permutation).
__device__ __forceinline__ void xcd_swizzle(int& bx, int& by) {
    const int nx = gridDim.x;
    const int rows_per_xcd = gridDim.y >> 3;
    const int flat = blockIdx.y * nx + blockIdx.x;
    const int xcd = flat & 7;
    const int i = flat >> 3;
    by = xcd * rows_per_xcd + i / nx;
    bx = i % nx;
}

// ------------- x fp32 -> bf16 bulk convert (8 elts/thread) --------------------
__global__ __launch_bounds__(256)
void cvt_f32_bf16(const float* __restrict__ in, unsigned short* __restrict__ out,
                  long long n8) {
    const long long i = ((long long)blockIdx.x * 256 + threadIdx.x) * 8;
    if (i >= n8) return;
    f32x4 a = *(const f32x4*)(in + i);
    f32x4 b = *(const f32x4*)(in + i + 4);
    short8 o;
    #pragma unroll
    for (int j = 0; j < 4; ++j) { o[j] = (short)f2b(a[j]); o[j + 4] = (short)f2b(b[j]); }
    *(short8*)(out + i) = o;
}

// ------------- transpose + fp32->bf16 convert (weights, once per launch) ------
__global__ __launch_bounds__(256)
void transpose_f32_bf16(const float* __restrict__ in, unsigned short* __restrict__ out,
                        int R, int C) {
    __shared__ unsigned short t[32][33];
    const int r0 = blockIdx.y * 32, c0 = blockIdx.x * 32;
    const int tx = threadIdx.x & 31, ty = threadIdx.x >> 5;
    #pragma unroll
    for (int i = 0; i < 32; i += 8)
        t[ty + i][tx] = f2b(in[(size_t)(r0 + ty + i) * C + c0 + tx]);
    __syncthreads();
    #pragma unroll
    for (int i = 0; i < 32; i += 8)
        out[(size_t)(c0 + ty + i) * R + r0 + tx] = t[tx][ty + i];
}

// =============================================================================
// 256-row deep-pipelined GEMM: C(MxN) = A(MxK) @ BT(NxK)^T, bf16 inputs.
// BK=32, 4-deep LDS ring buffer, counted vmcnt (never 0 in steady state),
// XOR-swizzled LDS (T2), setprio around MFMA (T5), XCD swizzle (T1).
// 8 waves = WM x WN; BN in {256,128}. M%256==0, N%BN==0, K%32==0 assumed.
// =============================================================================
template<int BN, bool F32OUT>
__global__ __launch_bounds__(512, 2)
void gemm256(const unsigned short* __restrict__ A,
             const unsigned short* __restrict__ BT,
             void* __restrict__ Cout, const float* __restrict__ bias,
             int M, int N, int K) {
    constexpr int WN    = BN / 64;      // warps along N: 4 or 2
    constexpr int WM    = 8 / WN;       // warps along M: 2 or 4
    constexpr int WROWS = 256 / WM;     // rows per wave: 128 or 64
    constexpr int MI    = WROWS / 16;   // A fragments per wave: 8 or 4
    constexpr int ABUF  = 256 * 32;     // elems per A ring slot (16 KiB)
    constexpr int BBUF  = BN * 32;      // elems per B ring slot

    __shared__ unsigned short As[4 * ABUF];
    __shared__ unsigned short Bs[4 * BBUF];

    int bxi, byi;
    xcd_swizzle(bxi, byi);
    const int bm = byi * 256, bn = bxi * BN;

    const int tid  = threadIdx.x;
    const int wave = tid >> 6, lane = tid & 63;
    const int quad = lane >> 4, m16 = lane & 15;
    const int wr = wave / WN, wc = wave % WN;

    // ---- staging addresses: linear LDS dest, inverse-swizzled global source --
    const int srow = (wave << 4) + (lane >> 2);   // 0..127 across the block
    const int chk  = lane & 3;                    // 16B chunk within 64B row
    const int sc   = (chk ^ (srow >> 1)) & 3;     // swizzled source chunk
    const unsigned short* gA0 = A  + (size_t)(bm + srow) * K + sc * 8;
    const unsigned short* gA1 = gA0 + (size_t)128 * K;   // rows 128..255 (same sc: 128>>1 ≡ 0 mod 4)
    const unsigned short* gB0 = BT + (size_t)(bn + srow) * K + sc * 8;
    const unsigned short* gB1 = gB0 + (size_t)128 * K;   // only used when BN==256

    // ---- swizzled ds_read byte offsets (within one ring slot) ----------------
    int aoff[MI], boff[4];
    #pragma unroll
    for (int i = 0; i < MI; ++i) {
        const int r = wr * WROWS + i * 16 + m16;
        aoff[i] = r * 64 + (((quad ^ (r >> 1)) & 3) << 4);
    }
    #pragma unroll
    for (int j = 0; j < 4; ++j) {
        const int r = wc * 64 + j * 16 + m16;
        boff[j] = r * 64 + (((quad ^ (r >> 1)) & 3) << 4);
    }

    const int NT = K >> 5;

    auto stage = [&](int t) {
        const int s = t & 3;
        unsigned short* Ab = As + s * ABUF + (wave << 9);
        unsigned short* Bb = Bs + s * BBUF + (wave << 9);
        const int ke = t << 5;
        async16(Ab,        gA0 + ke);
        async16(Ab + 4096, gA1 + ke);
        async16(Bb,        gB0 + ke);
        if constexpr (BN == 256) async16(Bb + 4096, gB1 + ke);
    };

    f32x4 acc[MI][4] = {};

    // prologue: stage tiles 0..2 (3-deep ring fill)
    const int npre = NT < 3 ? NT : 3;
    for (int t = 0; t < npre; ++t) stage(t);

    for (int t = 0; t < NT; ++t) {
        // wait until tile t's loads landed; keep t+1,t+2 in flight (T4)
        const int ahead = NT - 1 - t;
        if constexpr (BN == 256) {
            if (ahead >= 2)      asm volatile("s_waitcnt vmcnt(8)" ::: "memory");
            else if (ahead == 1) asm volatile("s_waitcnt vmcnt(4)" ::: "memory");
            else                 asm volatile("s_waitcnt vmcnt(0)" ::: "memory");
        } else {
            if (ahead >= 2)      asm volatile("s_waitcnt vmcnt(6)" ::: "memory");
            else if (ahead == 1) asm volatile("s_waitcnt vmcnt(3)" ::: "memory");
            else                 asm volatile("s_waitcnt vmcnt(0)" ::: "memory");
        }
        __builtin_amdgcn_s_barrier();
        asm volatile("" ::: "memory");   // keep LDS reads below the barrier

        // prefetch tile t+3 into the slot whose reads finished before the barrier
        if (t + 3 < NT) stage(t + 3);

        const char* Ab = (const char*)As + (t & 3) * (ABUF * 2);
        const char* Bb = (const char*)Bs + (t & 3) * (BBUF * 2);
        short8 af[MI], bfr[4];
        #pragma unroll
        for (int i = 0; i < MI; ++i) af[i] = *(const short8*)(Ab + aoff[i]);
        #pragma unroll
        for (int j = 0; j < 4; ++j)  bfr[j] = *(const short8*)(Bb + boff[j]);

        __builtin_amdgcn_s_setprio(1);
        #pragma unroll
        for (int i = 0; i < MI; ++i)
            #pragma unroll
            for (int j = 0; j < 4; ++j)
                acc[i][j] = __builtin_amdgcn_mfma_f32_16x16x32_bf16(af[i], bfr[j], acc[i][j], 0, 0, 0);
        __builtin_amdgcn_s_setprio(0);
    }

    if constexpr (F32OUT) {
        float* C = (float*)Cout;
        #pragma unroll
        for (int j = 0; j < 4; ++j) {
            const int col = bn + wc * 64 + j * 16 + m16;
            const float bv = bias[col];
            #pragma unroll
            for (int i = 0; i < MI; ++i)
                #pragma unroll
                for (int r = 0; r < 4; ++r) {
                    const int row = bm + wr * WROWS + i * 16 + quad * 4 + r;
                    C[(size_t)row * N + col] = acc[i][j][r] + bv;
                }
        }
    } else {
        unsigned short* C = (unsigned short*)Cout;
        #pragma unroll
        for (int j = 0; j < 4; ++j) {
            const int col = bn + wc * 64 + j * 16 + m16;
            #pragma unroll
            for (int i = 0; i < MI; ++i)
                #pragma unroll
                for (int r = 0; r < 4; ++r) {
                    const int row = bm + wr * WROWS + i * 16 + quad * 4 + r;
                    C[(size_t)row * N + col] = f2b(acc[i][j][r]);
                }
        }
    }
}

// ---- stage 2: S = K^T Q per (b,h) + col sumsq, split-K, b64 LDS reads --------
#define SPLIT 16
__global__ __launch_bounds__(256)
void kq_gram(const unsigned short* __restrict__ qkv,
             float* __restrict__ S, float* __restrict__ qn2, float* __restrict__ kn2) {
    const int bh = blockIdx.x / SPLIT;
    const int part = blockIdx.x % SPLIT;
    const int b = bh / 12, h = bh % 12;
    const int n0 = part * (4096 / SPLIT);      // 256 tokens per block
    __shared__ unsigned short Qs[64][72];
    __shared__ unsigned short Ks[64][72];
    const int tid = threadIdx.x;
    const int q0 = (tid & 15) * 4;
    const int p0 = (tid >> 4) * 4;
    float acc[4][4] = {};
    float qn[4] = {}, kn[4] = {};
    const int r = tid >> 2, cc = tid & 3;
    for (int nc = 0; nc < 256; nc += 64) {
        const unsigned short* qrow = qkv + (size_t)(b * 4096 + n0 + nc + r) * 2304 + h * 64;
        short8 v0 = *(const short8*)(qrow + cc * 8);
        short8 v1 = *(const short8*)(qrow + (cc + 4) * 8);
        short8 v2 = *(const short8*)(qrow + 768 + cc * 8);
        short8 v3 = *(const short8*)(qrow + 768 + (cc + 4) * 8);
        __syncthreads();
        *(short8*)&Qs[r][cc * 8]       = v0;
        *(short8*)&Qs[r][(cc + 4) * 8] = v1;
        *(short8*)&Ks[r][cc * 8]       = v2;
        *(short8*)&Ks[r][(cc + 4) * 8] = v3;
        __syncthreads();
        for (int n = 0; n < 64; ++n) {
            const ushort4v qu = *(const ushort4v*)&Qs[n][q0];   // one ds_read_b64
            const ushort4v ku = *(const ushort4v*)&Ks[n][p0];   // one ds_read_b64
            float qv[4], kv[4];
            #pragma unroll
            for (int j = 0; j < 4; ++j) qv[j] = b2f(qu[j]);
            #pragma unroll
            for (int i = 0; i < 4; ++i) kv[i] = b2f(ku[i]);
            #pragma unroll
            for (int i = 0; i < 4; ++i)
                #pragma unroll
                for (int j = 0; j < 4; ++j)
                    acc[i][j] += kv[i] * qv[j];
            if (p0 == 0) {
                #pragma unroll
                for (int j = 0; j < 4; ++j) qn[j] += qv[j] * qv[j];
            }
            if (q0 == 0) {
                #pragma unroll
                for (int i = 0; i < 4; ++i) kn[i] += kv[i] * kv[i];
            }
        }
    }
    float* Sb = S + (size_t)bh * 4096;
    #pragma unroll
    for (int i = 0; i < 4; ++i)
        #pragma unroll
        for (int j = 0; j < 4; ++j)
            atomicAdd(&Sb[(p0 + i) * 64 + q0 + j], acc[i][j]);
    if (p0 == 0)
        #pragma unroll
        for (int j = 0; j < 4; ++j) atomicAdd(&qn2[bh * 64 + q0 + j], qn[j]);
    if (q0 == 0)
        #pragma unroll
        for (int i = 0; i < 4; ++i) atomicAdd(&kn2[bh * 64 + p0 + i], kn[i]);
}

// ---- stage 3: logits = t*S/(|k||q|), row softmax, store attn^T (bf16) --------
__global__ __launch_bounds__(64)
void softmax_attn(const float* __restrict__ S, const float* __restrict__ qn2,
                  const float* __restrict__ kn2, const float* __restrict__ temp,
                  unsigned short* __restrict__ attnT) {
    const int bh = blockIdx.x, h = bh % 12, p = threadIdx.x;
    const float t = temp[h];
    const float knv = fmaxf(sqrtf(kn2[bh * 64 + p]), 1e-12f);
    const float* Sr = S + (size_t)bh * 4096 + p * 64;
    const float* qr = qn2 + bh * 64;
    float l[64];
    float mx = -1e30f;
    #pragma unroll
    for (int q = 0; q < 64; ++q) {
        const float qnv = fmaxf(sqrtf(qr[q]), 1e-12f);
        l[q] = t * Sr[q] / (knv * qnv);
        mx = fmaxf(mx, l[q]);
    }
    float sum = 0.f;
    #pragma unroll
    for (int q = 0; q < 64; ++q) { l[q] = __expf(l[q] - mx); sum += l[q]; }
    const float inv = 1.0f / sum;
    unsigned short* At = attnT + (size_t)bh * 4096;
    #pragma unroll
    for (int q = 0; q < 64; ++q) At[q * 64 + p] = f2b(l[q] * inv);
}

// ---- stage 4: O = V @ attn per (b,h), MFMA -----------------------------------
__global__ __launch_bounds__(256)
void av_gemm(const unsigned short* __restrict__ qkv, const unsigned short* __restrict__ attnT,
             unsigned short* __restrict__ O) {
    const int bh = blockIdx.y;
    const int b = bh / 12, h = bh % 12;
    const int n0 = blockIdx.x * 256;
    __shared__ unsigned short Vs[256][72];
    __shared__ unsigned short Ats[64][72];
    const int tid = threadIdx.x;
    const int wave = tid >> 6, lane = tid & 63;
    const int quad = lane >> 4, m16 = lane & 15;
    {
        const int r = tid >> 2, cc = tid & 3;
        const unsigned short* ap = attnT + (size_t)bh * 4096 + r * 64;
        *(short8*)&Ats[r][cc * 8]       = *(const short8*)(ap + cc * 8);
        *(short8*)&Ats[r][(cc + 4) * 8] = *(const short8*)(ap + (cc + 4) * 8);
        #pragma unroll
        for (int it = 0; it < 8; ++it) {
            const int idx = tid + it * 256;
            const int row = idx >> 3, c2 = (idx & 7) * 8;
            const unsigned short* vp = qkv + (size_t)(b * 4096 + n0 + row) * 2304 + 1536 + h * 64 + c2;
            *(short8*)&Vs[row][c2] = *(const short8*)vp;
        }
    }
    __syncthreads();
    f32x4 acc[4][4] = {};
    #pragma unroll
    for (int ks = 0; ks < 2; ++ks) {
        const int k0 = ks * 32;
        short8 af[4], bfr[4];
        #pragma unroll
        for (int i = 0; i < 4; ++i)
            af[i] = *(const short8*)&Vs[wave * 64 + i * 16 + m16][k0 + quad * 8];
        #pragma unroll
        for (int j = 0; j < 4; ++j)
            bfr[j] = *(const short8*)&Ats[j * 16 + m16][k0 + quad * 8];
        #pragma unroll
        for (int i = 0; i < 4; ++i)
            #pragma unroll
            for (int j = 0; j < 4; ++j)
                acc[i][j] = __builtin_amdgcn_mfma_f32_16x16x32_bf16(af[i], bfr[j], acc[i][j], 0, 0, 0);
    }
    #pragma unroll
    for (int i = 0; i < 4; ++i)
        #pragma unroll
        for (int j = 0; j < 4; ++j)
            #pragma unroll
            for (int r = 0; r < 4; ++r) {
                const int row = n0 + wave * 64 + i * 16 + quad * 4 + r;
                O[(size_t)(b * 4096 + row) * 768 + h * 64 + j * 16 + m16] = f2b(acc[i][j][r]);
            }
}

extern "C" void kernel_launch(void* const* d_in, const int* in_sizes, int n_in,
                              void* d_out, int out_size, void* d_ws, size_t ws_size,
                              hipStream_t stream) {
    const float *x = nullptr, *Wqkv = nullptr, *temp = nullptr, *Wout = nullptr, *bout = nullptr;
    for (int i = 0; i < n_in; ++i) {
        switch (in_sizes[i]) {
            case 25165824: x    = (const float*)d_in[i]; break;  // 8*4096*768
            case 1769472:  Wqkv = (const float*)d_in[i]; break;  // 768*2304
            case 12:       temp = (const float*)d_in[i]; break;  // (1,12,1,1)
            case 589824:   Wout = (const float*)d_in[i]; break;  // 768*768
            case 768:      bout = (const float*)d_in[i]; break;  // (768,)
        }
    }
    float* out = (float*)d_out;  // (8,4096,768) fp32

    char* ws = (char*)d_ws;
    unsigned short* WqkvT = (unsigned short*)(ws);                // 3,538,944 B
    unsigned short* WoutT = (unsigned short*)(ws + 3538944);      // 1,179,648 B
    const size_t base = 4718592;

    // Per-batch: xb 6,291,456 + qkv 18,874,368 + O 6,291,456 + attnT 98,304 +
    //            S 196,608 + qn2 3,072 + kn2 3,072 = 31,758,336
    const size_t perb = 31758336;
    int c = 1;
    if      (base + 8 * perb <= ws_size) c = 8;
    else if (base + 4 * perb <= ws_size) c = 4;
    else if (base + 2 * perb <= ws_size) c = 2;

    char* ca = ws + base;
    unsigned short* xb    = (unsigned short*)(ca);
    unsigned short* qkv   = (unsigned short*)(ca + (size_t)c * 6291456);
    unsigned short* O     = (unsigned short*)(ca + (size_t)c * 25165824);
    unsigned short* attnT = (unsigned short*)(ca + (size_t)c * 31457280);
    char*  Sz             =                   ca + (size_t)c * 31555584;
    float* S              = (float*)Sz;
    float* qn2            = (float*)(Sz + (size_t)c * 196608);
    float* kn2            = (float*)(Sz + (size_t)c * (196608 + 3072));

    transpose_f32_bf16<<<dim3(2304 / 32, 768 / 32), 256, 0, stream>>>(Wqkv, WqkvT, 768, 2304);
    transpose_f32_bf16<<<dim3(768 / 32, 768 / 32), 256, 0, stream>>>(Wout, WoutT, 768, 768);

    for (int b0 = 0; b0 < 8; b0 += c) {
        const int nb = c;  // 8 % c == 0
        hipMemsetAsync(Sz, 0, (size_t)nb * (196608 + 3072 + 3072), stream);

        // stage 0: x chunk -> bf16
        const long long n8 = (long long)nb * 3145728;
        cvt_f32_bf16<<<dim3((unsigned)(n8 / 8 / 256)), 256, 0, stream>>>(
            x + (size_t)b0 * 3145728, xb, n8);

        // stage 1: qkv = xb @ WqkvT^T  (M=nb*4096, N=2304, K=768) — 256-tile pipelined
        gemm256<256, false><<<dim3(2304 / 256, nb * 16), 512, 0, stream>>>(
            xb, WqkvT, qkv, nullptr, nb * 4096, 2304, 768);

        // stage 2: per-(b,h) Gram + norms
        kq_gram<<<dim3(nb * 12 * SPLIT), 256, 0, stream>>>(qkv, S, qn2, kn2);

        // stage 3: scaled softmax -> attn^T bf16
        softmax_attn<<<dim3(nb * 12), 64, 0, stream>>>(S, qn2, kn2, temp, attnT);

        // stage 4: O = V @ attn -> bf16
        av_gemm<<<dim3(4096 / 256, nb * 12), 256, 0, stream>>>(qkv, attnT, O);

        // stage 5: out = O @ WoutT^T + bout -> fp32 (BN=128: 768 blocks = 3/CU exact)
        gemm256<128, true><<<dim3(768 / 128, nb * 16), 512, 0, stream>>>(
            O, WoutT, out + (size_t)b0 * 3145728, bout, nb * 4096, 768, 768);
    }
}

// Round 2
// 563.722 us; speedup vs baseline: 1.0735x; 1.0735x over previous
//
#include <hip/hip_runtime.h>

typedef __attribute__((ext_vector_type(8))) short short8;
typedef __attribute__((ext_vector_type(4))) unsigned short ushort4v;
typedef __attribute__((ext_vector_type(4))) float f32x4;

__device__ __forceinline__ float b2f(unsigned short u) {
    unsigned int i = ((unsigned int)u) << 16;
    return __builtin_bit_cast(float, i);
}
__device__ __forceinline__ unsigned short f2b(float f) {
    unsigned int u = __builtin_bit_cast(unsigned int, f);
    unsigned int r = (u + 0x7fffu + ((u >> 16) & 1u)) >> 16;
    return (unsigned short)r;
}

// async 16B global->LDS copy; lds base must be wave-uniform (HW adds lane*16B)
__device__ __forceinline__ void async16(unsigned short* lds, const unsigned short* g) {
    __builtin_amdgcn_global_load_lds(
        (const __attribute__((address_space(1))) unsigned int*)g,
        (__attribute__((address_space(3))) unsigned int*)lds,
        16, 0, 0);
}

// XCD-aware block swizzle (gridDim.y % 8 == 0 required; pure permutation).
__device__ __forceinline__ void xcd_swizzle(int& bx, int& by) {
    const int nx = gridDim.x;
    const int rows_per_xcd = gridDim.y >> 3;
    const int flat = blockIdx.y * nx + blockIdx.x;
    const int xcd = flat & 7;
    const int i = flat >> 3;
    by = xcd * rows_per_xcd + i / nx;
    bx = i % nx;
}

// ------------- x fp32 -> bf16 bulk convert (8 elts/thread) --------------------
__global__ __launch_bounds__(256)
void cvt_f32_bf16(const float* __restrict__ in, unsigned short* __restrict__ out,
                  long long n8) {
    const long long i = ((long long)blockIdx.x * 256 + threadIdx.x) * 8;
    if (i >= n8) return;
    f32x4 a = *(const f32x4*)(in + i);
    f32x4 b = *(const f32x4*)(in + i + 4);
    short8 o;
    #pragma unroll
    for (int j = 0; j < 4; ++j) { o[j] = (short)f2b(a[j]); o[j + 4] = (short)f2b(b[j]); }
    *(short8*)(out + i) = o;
}

// ------------- transpose + fp32->bf16 convert (weights, once per launch) ------
__global__ __launch_bounds__(256)
void transpose_f32_bf16(const float* __restrict__ in, unsigned short* __restrict__ out,
                        int R, int C) {
    __shared__ unsigned short t[32][33];
    const int r0 = blockIdx.y * 32, c0 = blockIdx.x * 32;
    const int tx = threadIdx.x & 31, ty = threadIdx.x >> 5;
    #pragma unroll
    for (int i = 0; i < 32; i += 8)
        t[ty + i][tx] = f2b(in[(size_t)(r0 + ty + i) * C + c0 + tx]);
    __syncthreads();
    #pragma unroll
    for (int i = 0; i < 32; i += 8)
        out[(size_t)(c0 + ty + i) * R + r0 + tx] = t[tx][ty + i];
}

// =============================================================================
// 256x256 8-phase GEMM (m201-style): C = A(MxK) @ BT(NxK)^T, bf16 in.
// BK=64, double-buffered half-tile LDS (128 KiB), 8 waves (2M x 4N),
// per-wave C = 128x64. Per phase: {ds_read subtile || stage half-tile} ->
// barrier -> lgkmcnt(0) -> setprio(1) 16xMFMA setprio(0) -> barrier.
// vmcnt(4) only at phases 4 & 8 (before closing barrier). LDS swizzle:
// 16B-chunk ^= row&7 (2-way/quarter = free), source-side pre-swizzle.
// Requires M%256==0, N%256==0, K%128==0.
// =============================================================================
#define BARX  { __builtin_amdgcn_s_barrier(); asm volatile("" ::: "memory"); }
#define LGKM0 { asm volatile("s_waitcnt lgkmcnt(0)" ::: "memory"); __builtin_amdgcn_sched_barrier(0); }
#define VMC4  asm volatile("s_waitcnt vmcnt(4)" ::: "memory")
#define VMC0  asm volatile("s_waitcnt vmcnt(0)" ::: "memory")

#define RD_A(lo, bufoff) { \
    _Pragma("unroll") for (int q = 0; q < 4; ++q) { \
        a[q][0] = *(const short8*)(Ab + (bufoff) + aks0 + ((lo) + q) * 2048); \
        a[q][1] = *(const short8*)(Ab + (bufoff) + aks1 + ((lo) + q) * 2048); } }
#define RD_B(lo, bufoff) { \
    _Pragma("unroll") for (int n = 0; n < 2; ++n) { \
        bb[(lo) + n][0] = *(const short8*)(Bb + (bufoff) + bks0 + ((lo) + n) * 2048); \
        bb[(lo) + n][1] = *(const short8*)(Bb + (bufoff) + bks1 + ((lo) + n) * 2048); } }
#define MFMA8(qo, no) { \
    __builtin_amdgcn_s_setprio(1); \
    _Pragma("unroll") for (int q = 0; q < 4; ++q) \
        _Pragma("unroll") for (int n = 0; n < 2; ++n) { \
            acc[(qo) + q][(no) + n] = __builtin_amdgcn_mfma_f32_16x16x32_bf16( \
                a[q][0], bb[(no) + n][0], acc[(qo) + q][(no) + n], 0, 0, 0); \
            acc[(qo) + q][(no) + n] = __builtin_amdgcn_mfma_f32_16x16x32_bf16( \
                a[q][1], bb[(no) + n][1], acc[(qo) + q][(no) + n], 0, 0, 0); } \
    __builtin_amdgcn_s_setprio(0); }

template<bool F32OUT>
__global__ __launch_bounds__(512, 2)
void gemm256_8ph(const unsigned short* __restrict__ A,
                 const unsigned short* __restrict__ BT,
                 void* __restrict__ Cout, const float* __restrict__ bias,
                 int M, int N, int K) {
    // [buf][half][row 128][chunk 8][16B]; buf stride 16384 elems (32768 B)
    __shared__ __attribute__((aligned(16))) unsigned short As[32768];
    __shared__ __attribute__((aligned(16))) unsigned short Bs[32768];

    int bxi, byi;
    xcd_swizzle(bxi, byi);
    const int bm = byi * 256, bn = bxi * 256;

    const int tid  = threadIdx.x;
    const int wave = tid >> 6, lane = tid & 63;
    const int quad = lane >> 4, m16 = lane & 15;
    const int wr = wave >> 2, wc = wave & 3;   // 2 x 4 wave grid

    // ---- staging: linear LDS dest, inverse-swizzled global source ------------
    const int srow = tid >> 3;                       // 0..63
    const int schk = (tid & 7) ^ (srow & 7);         // swizzled 16B chunk
    const unsigned short* gA = A  + (size_t)(bm + srow) * K + schk * 8;
    const unsigned short* gB = BT + (size_t)(bn + srow) * K + schk * 8;
    unsigned short* ldsA0 = As + wave * 512;
    unsigned short* ldsB0 = Bs + wave * 512;

    auto SA = [&](int buf, int half, int kt) {
        unsigned short* d = ldsA0 + buf * 16384 + half * 8192;
        const unsigned short* s = gA + (size_t)half * 128 * K + kt * 64;
        async16(d, s);
        async16(d + 4096, s + (size_t)64 * K);
    };
    auto SB = [&](int buf, int half, int kt) {
        unsigned short* d = ldsB0 + buf * 16384 + half * 8192;
        const unsigned short* s = gB + (size_t)half * 128 * K + kt * 64;
        async16(d, s);
        async16(d + 4096, s + (size_t)64 * K);
    };

    // ---- swizzled ds_read byte offsets ---------------------------------------
    const int e    = m16 & 7;
    const int csw  = (quad ^ e) << 4;                       // ks=0 chunk byte
    const int aks0 = wr * 16384 + m16 * 128 + csw;          // +mi*2048
    const int aks1 = aks0 ^ 64;                             // ks=1 (chunk^4)
    const int bks0 = (wc >> 1) * 16384 + ((wc & 1) * 64 + m16) * 128 + csw;
    const int bks1 = bks0 ^ 64;
    const char* Ab = (const char*)As;
    const char* Bb = (const char*)Bs;

    short8 a[4][2], bb[4][2];
    f32x4 acc[8][4] = {};

    const int ITERS = K >> 7;   // K/128 (two BK=64 tiles per iteration)

    // prologue: buf0 <- tile 0 (B,A), buf1.B <- tile 1; 12 loads in flight
    SB(0, 0, 0); SB(0, 1, 0); SA(0, 0, 0); SA(0, 1, 0);
    SB(1, 0, 1); SB(1, 1, 1);
    VMC4;        // buf0 fully landed (4 newest = buf1.B may stay in flight)
    BARX;

    for (int it = 0; it < ITERS; ++it) {
        const int kt0 = 2 * it, kt1 = kt0 + 1;
        const bool nl = (it + 1 < ITERS);
        // -------- phase 1: A0-3,B0-1 of buf0 | stage buf1.Ah0 <- kt1 ---------
        RD_A(0, 0) RD_B(0, 0)
        SA(1, 0, kt1);
        BARX; LGKM0; MFMA8(0, 0); BARX;
        // -------- phase 2: B2-3 | stage buf1.Ah1 <- kt1 ----------------------
        RD_B(2, 0)
        SA(1, 1, kt1);
        BARX; LGKM0; MFMA8(0, 2); BARX;
        // -------- phase 3: A4-7 | stage buf0.Bh0 <- kt0+2 --------------------
        RD_A(4, 0)
        if (nl) SB(0, 0, kt0 + 2);
        BARX; LGKM0; MFMA8(4, 2); BARX;
        // -------- phase 4: stage buf0.Bh1 | vmcnt(4): buf1 published ---------
        if (nl) SB(0, 1, kt0 + 2);
        BARX; MFMA8(4, 0);
        if (nl) { VMC4; } else { VMC0; }
        BARX;
        // -------- phase 5: A0-3,B0-1 of buf1 | stage buf0.Ah0 <- kt0+2 -------
        RD_A(0, 32768) RD_B(0, 32768)
        if (nl) SA(0, 0, kt0 + 2);
        BARX; LGKM0; MFMA8(0, 0); BARX;
        // -------- phase 6: B2-3 | stage buf0.Ah1 -----------------------------
        RD_B(2, 32768)
        if (nl) SA(0, 1, kt0 + 2);
        BARX; LGKM0; MFMA8(0, 2); BARX;
        // -------- phase 7: A4-7 | stage buf1.Bh0 <- kt1+2 --------------------
        RD_A(4, 32768)
        if (nl) SB(1, 0, kt1 + 2);
        BARX; LGKM0; MFMA8(4, 2); BARX;
        // -------- phase 8: stage buf1.Bh1 | vmcnt(4): buf0 published ---------
        if (nl) SB(1, 1, kt1 + 2);
        BARX; MFMA8(4, 0);
        if (nl) { VMC4; } else { VMC0; }
        BARX;
    }

    if constexpr (F32OUT) {
        float* C = (float*)Cout;
        #pragma unroll
        for (int j = 0; j < 4; ++j) {
            const int col = bn + wc * 64 + j * 16 + m16;
            const float bv = bias[col];
            #pragma unroll
            for (int i = 0; i < 8; ++i)
                #pragma unroll
                for (int r = 0; r < 4; ++r) {
                    const int row = bm + wr * 128 + i * 16 + quad * 4 + r;
                    C[(size_t)row * N + col] = acc[i][j][r] + bv;
                }
        }
    } else {
        unsigned short* C = (unsigned short*)Cout;
        #pragma unroll
        for (int j = 0; j < 4; ++j) {
            const int col = bn + wc * 64 + j * 16 + m16;
            #pragma unroll
            for (int i = 0; i < 8; ++i)
                #pragma unroll
                for (int r = 0; r < 4; ++r) {
                    const int row = bm + wr * 128 + i * 16 + quad * 4 + r;
                    C[(size_t)row * N + col] = f2b(acc[i][j][r]);
                }
        }
    }
}

// ---- stage 2: S = K^T Q per (b,h) + col sumsq, split-K, b64 LDS reads --------
#define SPLIT 16
__global__ __launch_bounds__(256)
void kq_gram(const unsigned short* __restrict__ qkv,
             float* __restrict__ S, float* __restrict__ qn2, float* __restrict__ kn2) {
    const int bh = blockIdx.x / SPLIT;
    const int part = blockIdx.x % SPLIT;
    const int b = bh / 12, h = bh % 12;
    const int n0 = part * (4096 / SPLIT);      // 256 tokens per block
    __shared__ unsigned short Qs[64][72];
    __shared__ unsigned short Ks[64][72];
    const int tid = threadIdx.x;
    const int q0 = (tid & 15) * 4;
    const int p0 = (tid >> 4) * 4;
    float acc[4][4] = {};
    float qn[4] = {}, kn[4] = {};
    const int r = tid >> 2, cc = tid & 3;
    for (int nc = 0; nc < 256; nc += 64) {
        const unsigned short* qrow = qkv + (size_t)(b * 4096 + n0 + nc + r) * 2304 + h * 64;
        short8 v0 = *(const short8*)(qrow + cc * 8);
        short8 v1 = *(const short8*)(qrow + (cc + 4) * 8);
        short8 v2 = *(const short8*)(qrow + 768 + cc * 8);
        short8 v3 = *(const short8*)(qrow + 768 + (cc + 4) * 8);
        __syncthreads();
        *(short8*)&Qs[r][cc * 8]       = v0;
        *(short8*)&Qs[r][(cc + 4) * 8] = v1;
        *(short8*)&Ks[r][cc * 8]       = v2;
        *(short8*)&Ks[r][(cc + 4) * 8] = v3;
        __syncthreads();
        for (int n = 0; n < 64; ++n) {
            const ushort4v qu = *(const ushort4v*)&Qs[n][q0];   // one ds_read_b64
            const ushort4v ku = *(const ushort4v*)&Ks[n][p0];   // one ds_read_b64
            float qv[4], kv[4];
            #pragma unroll
            for (int j = 0; j < 4; ++j) qv[j] = b2f(qu[j]);
            #pragma unroll
            for (int i = 0; i < 4; ++i) kv[i] = b2f(ku[i]);
            #pragma unroll
            for (int i = 0; i < 4; ++i)
                #pragma unroll
                for (int j = 0; j < 4; ++j)
                    acc[i][j] += kv[i] * qv[j];
            if (p0 == 0) {
                #pragma unroll
                for (int j = 0; j < 4; ++j) qn[j] += qv[j] * qv[j];
            }
            if (q0 == 0) {
                #pragma unroll
                for (int i = 0; i < 4; ++i) kn[i] += kv[i] * kv[i];
            }
        }
    }
    float* Sb = S + (size_t)bh * 4096;
    #pragma unroll
    for (int i = 0; i < 4; ++i)
        #pragma unroll
        for (int j = 0; j < 4; ++j)
            atomicAdd(&Sb[(p0 + i) * 64 + q0 + j], acc[i][j]);
    if (p0 == 0)
        #pragma unroll
        for (int j = 0; j < 4; ++j) atomicAdd(&qn2[bh * 64 + q0 + j], qn[j]);
    if (q0 == 0)
        #pragma unroll
        for (int i = 0; i < 4; ++i) atomicAdd(&kn2[bh * 64 + p0 + i], kn[i]);
}

// ---- stage 3: logits = t*S/(|k||q|), row softmax, store attn^T (bf16) --------
__global__ __launch_bounds__(64)
void softmax_attn(const float* __restrict__ S, const float* __restrict__ qn2,
                  const float* __restrict__ kn2, const float* __restrict__ temp,
                  unsigned short* __restrict__ attnT) {
    const int bh = blockIdx.x, h = bh % 12, p = threadIdx.x;
    const float t = temp[h];
    const float knv = fmaxf(sqrtf(kn2[bh * 64 + p]), 1e-12f);
    const float* Sr = S + (size_t)bh * 4096 + p * 64;
    const float* qr = qn2 + bh * 64;
    float l[64];
    float mx = -1e30f;
    #pragma unroll
    for (int q = 0; q < 64; ++q) {
        const float qnv = fmaxf(sqrtf(qr[q]), 1e-12f);
        l[q] = t * Sr[q] / (knv * qnv);
        mx = fmaxf(mx, l[q]);
    }
    float sum = 0.f;
    #pragma unroll
    for (int q = 0; q < 64; ++q) { l[q] = __expf(l[q] - mx); sum += l[q]; }
    const float inv = 1.0f / sum;
    unsigned short* At = attnT + (size_t)bh * 4096;
    #pragma unroll
    for (int q = 0; q < 64; ++q) At[q * 64 + p] = f2b(l[q] * inv);
}

// ---- stage 4: O = V @ attn per (b,h), MFMA -----------------------------------
__global__ __launch_bounds__(256)
void av_gemm(const unsigned short* __restrict__ qkv, const unsigned short* __restrict__ attnT,
             unsigned short* __restrict__ O) {
    const int bh = blockIdx.y;
    const int b = bh / 12, h = bh % 12;
    const int n0 = blockIdx.x * 256;
    __shared__ unsigned short Vs[256][72];
    __shared__ unsigned short Ats[64][72];
    const int tid = threadIdx.x;
    const int wave = tid >> 6, lane = tid & 63;
    const int quad = lane >> 4, m16 = lane & 15;
    {
        const int r = tid >> 2, cc = tid & 3;
        const unsigned short* ap = attnT + (size_t)bh * 4096 + r * 64;
        *(short8*)&Ats[r][cc * 8]       = *(const short8*)(ap + cc * 8);
        *(short8*)&Ats[r][(cc + 4) * 8] = *(const short8*)(ap + (cc + 4) * 8);
        #pragma unroll
        for (int it = 0; it < 8; ++it) {
            const int idx = tid + it * 256;
            const int row = idx >> 3, c2 = (idx & 7) * 8;
            const unsigned short* vp = qkv + (size_t)(b * 4096 + n0 + row) * 2304 + 1536 + h * 64 + c2;
            *(short8*)&Vs[row][c2] = *(const short8*)vp;
        }
    }
    __syncthreads();
    f32x4 acc[4][4] = {};
    #pragma unroll
    for (int ks = 0; ks < 2; ++ks) {
        const int k0 = ks * 32;
        short8 af[4], bfr[4];
        #pragma unroll
        for (int i = 0; i < 4; ++i)
            af[i] = *(const short8*)&Vs[wave * 64 + i * 16 + m16][k0 + quad * 8];
        #pragma unroll
        for (int j = 0; j < 4; ++j)
            bfr[j] = *(const short8*)&Ats[j * 16 + m16][k0 + quad * 8];
        #pragma unroll
        for (int i = 0; i < 4; ++i)
            #pragma unroll
            for (int j = 0; j < 4; ++j)
                acc[i][j] = __builtin_amdgcn_mfma_f32_16x16x32_bf16(af[i], bfr[j], acc[i][j], 0, 0, 0);
    }
    #pragma unroll
    for (int i = 0; i < 4; ++i)
        #pragma unroll
        for (int j = 0; j < 4; ++j)
            #pragma unroll
            for (int r = 0; r < 4; ++r) {
                const int row = n0 + wave * 64 + i * 16 + quad * 4 + r;
                O[(size_t)(b * 4096 + row) * 768 + h * 64 + j * 16 + m16] = f2b(acc[i][j][r]);
            }
}

extern "C" void kernel_launch(void* const* d_in, const int* in_sizes, int n_in,
                              void* d_out, int out_size, void* d_ws, size_t ws_size,
                              hipStream_t stream) {
    const float *x = nullptr, *Wqkv = nullptr, *temp = nullptr, *Wout = nullptr, *bout = nullptr;
    for (int i = 0; i < n_in; ++i) {
        switch (in_sizes[i]) {
            case 25165824: x    = (const float*)d_in[i]; break;  // 8*4096*768
            case 1769472:  Wqkv = (const float*)d_in[i]; break;  // 768*2304
            case 12:       temp = (const float*)d_in[i]; break;  // (1,12,1,1)
            case 589824:   Wout = (const float*)d_in[i]; break;  // 768*768
            case 768:      bout = (const float*)d_in[i]; break;  // (768,)
        }
    }
    float* out = (float*)d_out;  // (8,4096,768) fp32

    char* ws = (char*)d_ws;
    unsigned short* WqkvT = (unsigned short*)(ws);                // 3,538,944 B
    unsigned short* WoutT = (unsigned short*)(ws + 3538944);      // 1,179,648 B
    const size_t base = 4718592;

    // Per-batch: xb 6,291,456 + qkv 18,874,368 + O 6,291,456 + attnT 98,304 +
    //            S 196,608 + qn2 3,072 + kn2 3,072 = 31,758,336
    const size_t perb = 31758336;
    int c = 1;
    if      (base + 8 * perb <= ws_size) c = 8;
    else if (base + 4 * perb <= ws_size) c = 4;
    else if (base + 2 * perb <= ws_size) c = 2;

    char* ca = ws + base;
    unsigned short* xb    = (unsigned short*)(ca);
    unsigned short* qkv   = (unsigned short*)(ca + (size_t)c * 6291456);
    unsigned short* O     = (unsigned short*)(ca + (size_t)c * 25165824);
    unsigned short* attnT = (unsigned short*)(ca + (size_t)c * 31457280);
    char*  Sz             =                   ca + (size_t)c * 31555584;
    float* S              = (float*)Sz;
    float* qn2            = (float*)(Sz + (size_t)c * 196608);
    float* kn2            = (float*)(Sz + (size_t)c * (196608 + 3072));

    transpose_f32_bf16<<<dim3(2304 / 32, 768 / 32), 256, 0, stream>>>(Wqkv, WqkvT, 768, 2304);
    transpose_f32_bf16<<<dim3(768 / 32, 768 / 32), 256, 0, stream>>>(Wout, WoutT, 768, 768);

    for (int b0 = 0; b0 < 8; b0 += c) {
        const int nb = c;  // 8 % c == 0
        hipMemsetAsync(Sz, 0, (size_t)nb * (196608 + 3072 + 3072), stream);

        // stage 0: x chunk -> bf16
        const long long n8 = (long long)nb * 3145728;
        cvt_f32_bf16<<<dim3((unsigned)(n8 / 8 / 256)), 256, 0, stream>>>(
            x + (size_t)b0 * 3145728, xb, n8);

        // stage 1: qkv = xb @ WqkvT^T  (M=nb*4096, N=2304, K=768) — 8-phase 256²
        gemm256_8ph<false><<<dim3(2304 / 256, nb * 16), 512, 0, stream>>>(
            xb, WqkvT, qkv, nullptr, nb * 4096, 2304, 768);

        // stage 2: per-(b,h) Gram + norms
        kq_gram<<<dim3(nb * 12 * SPLIT), 256, 0, stream>>>(qkv, S, qn2, kn2);

        // stage 3: scaled softmax -> attn^T bf16
        softmax_attn<<<dim3(nb * 12), 64, 0, stream>>>(S, qn2, kn2, temp, attnT);

        // stage 4: O = V @ attn -> bf16
        av_gemm<<<dim3(4096 / 256, nb * 12), 256, 0, stream>>>(qkv, attnT, O);

        // stage 5: out = O @ WoutT^T + bout -> fp32 — 8-phase 256²
        gemm256_8ph<true><<<dim3(768 / 256, nb * 16), 512, 0, stream>>>(
            O, WoutT, out + (size_t)b0 * 3145728, bout, nb * 4096, 768, 768);
    }
}

// Round 3
// 449.394 us; speedup vs baseline: 1.3466x; 1.2544x over previous
//
#include <hip/hip_runtime.h>

typedef __attribute__((ext_vector_type(8))) short short8;
typedef __attribute__((ext_vector_type(4))) float f32x4;

__device__ __forceinline__ float b2f(unsigned short u) {
    unsigned int i = ((unsigned int)u) << 16;
    return __builtin_bit_cast(float, i);
}
__device__ __forceinline__ unsigned short f2b(float f) {
    unsigned int u = __builtin_bit_cast(unsigned int, f);
    unsigned int r = (u + 0x7fffu + ((u >> 16) & 1u)) >> 16;
    return (unsigned short)r;
}

// async 16B global->LDS copy; lds base must be wave-uniform (HW adds lane*16B)
__device__ __forceinline__ void async16(unsigned short* lds, const unsigned short* g) {
    __builtin_amdgcn_global_load_lds(
        (const __attribute__((address_space(1))) unsigned int*)g,
        (__attribute__((address_space(3))) unsigned int*)lds,
        16, 0, 0);
}

// XCD-aware block swizzle; only applied when gridDim.y % 8 == 0 (bijective).
__device__ __forceinline__ void xcd_swizzle(int& bx, int& by) {
    if ((gridDim.y & 7) == 0) {
        const int nx = gridDim.x;
        const int rows_per_xcd = gridDim.y >> 3;
        const int flat = blockIdx.y * nx + blockIdx.x;
        const int xcd = flat & 7;
        const int i = flat >> 3;
        by = xcd * rows_per_xcd + i / nx;
        bx = i % nx;
    } else {
        bx = blockIdx.x; by = blockIdx.y;
    }
}

// ------------- fp32 -> bf16 bulk convert (8 elts/thread) ----------------------
__global__ __launch_bounds__(256)
void cvt_f32_bf16(const float* __restrict__ in, unsigned short* __restrict__ out,
                  long long n8) {
    const long long i = ((long long)blockIdx.x * 256 + threadIdx.x) * 8;
    if (i >= n8) return;
    f32x4 a = *(const f32x4*)(in + i);
    f32x4 b = *(const f32x4*)(in + i + 4);
    short8 o;
    #pragma unroll
    for (int j = 0; j < 4; ++j) { o[j] = (short)f2b(a[j]); o[j + 4] = (short)f2b(b[j]); }
    *(short8*)(out + i) = o;
}

// ------------- transpose + fp32->bf16 convert (weights) -----------------------
__global__ __launch_bounds__(256)
void transpose_f32_bf16(const float* __restrict__ in, unsigned short* __restrict__ out,
                        int R, int C) {
    __shared__ unsigned short t[32][33];
    const int r0 = blockIdx.y * 32, c0 = blockIdx.x * 32;
    const int tx = threadIdx.x & 31, ty = threadIdx.x >> 5;
    #pragma unroll
    for (int i = 0; i < 32; i += 8)
        t[ty + i][tx] = f2b(in[(size_t)(r0 + ty + i) * C + c0 + tx]);
    __syncthreads();
    #pragma unroll
    for (int i = 0; i < 32; i += 8)
        out[(size_t)(c0 + ty + i) * R + r0 + tx] = t[tx][ty + i];
}

// ------------- x: fused fp32->bf16 convert (row-major) + transpose ------------
// in: (32768 x 768) fp32.  rm: (32768 x 768) bf16.  tm: (768 x 32768) bf16.
__global__ __launch_bounds__(256)
void cvt_tr(const float* __restrict__ in, unsigned short* __restrict__ rm,
            unsigned short* __restrict__ tm) {
    __shared__ unsigned short t[32][33];
    const int r0 = blockIdx.y * 32, c0 = blockIdx.x * 32;
    const int tx = threadIdx.x & 31, ty = threadIdx.x >> 5;
    #pragma unroll
    for (int i = 0; i < 32; i += 8) {
        unsigned short v = f2b(in[(size_t)(r0 + ty + i) * 768 + c0 + tx]);
        t[ty + i][tx] = v;
        rm[(size_t)(r0 + ty + i) * 768 + c0 + tx] = v;
    }
    __syncthreads();
    #pragma unroll
    for (int i = 0; i < 32; i += 8)
        tm[(size_t)(c0 + ty + i) * 32768 + r0 + tx] = t[tx][ty + i];
}

// =============================================================================
// Generalized m97-style GEMM: C = A @ BT^T (bf16 in), 128x128 tile, BK=32,
// 4 waves, global_load_lds staging, batched over blockIdx.z with element
// strides. lda/ldb/ldc are row strides (K-contiguous operands).
// OM: 0 = bf16 out, 1 = f32 out, 2 = f32 out + bias[col].
// Requires: tiles exactly cover (grid sized by caller), K % 32 == 0.
// =============================================================================
template<int OM>
__global__ __launch_bounds__(256, 2)
void gemm_bt_g(const unsigned short* A, const unsigned short* BT,
               void* __restrict__ Cv, const float* __restrict__ bias,
               int K, int lda, int ldb, int ldc,
               long long sA, long long sB, long long sC) {
    __shared__ unsigned short As[128 * 32];
    __shared__ unsigned short Bs[128 * 32];
    const int z = blockIdx.z;
    A  += (size_t)z * sA;
    BT += (size_t)z * sB;
    int bxi, byi;
    xcd_swizzle(bxi, byi);
    const int tid  = threadIdx.x;
    const int wave = tid >> 6, lane = tid & 63;
    const int quad = lane >> 4, m16 = lane & 15;
    const int bm = byi * 128, bn = bxi * 128;
    const int wm = (wave >> 1) * 64, wn = (wave & 1) * 64;
    const int srow = wave * 32 + (lane >> 2);
    const int scol = (lane & 3) * 8;
    const unsigned short* Ag = A + (size_t)(bm + srow) * lda + scol;
    const unsigned short* Bg = BT + (size_t)(bn + srow) * ldb + scol;
    unsigned short* Asw = &As[(wave * 32) * 32];
    unsigned short* Bsw = &Bs[(wave * 32) * 32];
    f32x4 acc[4][4] = {};

    for (int k0 = 0; k0 < K; k0 += 32) {
        __syncthreads();
        async16(Asw,           Ag + k0);
        async16(Asw + 16 * 32, Ag + k0 + (size_t)16 * lda);
        async16(Bsw,           Bg + k0);
        async16(Bsw + 16 * 32, Bg + k0 + (size_t)16 * ldb);
        __syncthreads();
        short8 af[4], bfr[4];
        #pragma unroll
        for (int i = 0; i < 4; ++i)
            af[i] = *(const short8*)&As[(wm + i * 16 + m16) * 32 + quad * 8];
        #pragma unroll
        for (int j = 0; j < 4; ++j)
            bfr[j] = *(const short8*)&Bs[(wn + j * 16 + m16) * 32 + quad * 8];
        #pragma unroll
        for (int i = 0; i < 4; ++i)
            #pragma unroll
            for (int j = 0; j < 4; ++j)
                acc[i][j] = __builtin_amdgcn_mfma_f32_16x16x32_bf16(af[i], bfr[j], acc[i][j], 0, 0, 0);
    }

    if constexpr (OM == 0) {
        unsigned short* C = (unsigned short*)Cv + (size_t)z * sC;
        #pragma unroll
        for (int j = 0; j < 4; ++j) {
            const int col = bn + wn + j * 16 + m16;
            #pragma unroll
            for (int i = 0; i < 4; ++i)
                #pragma unroll
                for (int r = 0; r < 4; ++r) {
                    const int row = bm + wm + i * 16 + quad * 4 + r;
                    C[(size_t)row * ldc + col] = f2b(acc[i][j][r]);
                }
        }
    } else {
        float* C = (float*)Cv + (size_t)z * sC;
        #pragma unroll
        for (int j = 0; j < 4; ++j) {
            const int col = bn + wn + j * 16 + m16;
            const float bv = (OM == 2) ? bias[col] : 0.0f;
            #pragma unroll
            for (int i = 0; i < 4; ++i)
                #pragma unroll
                for (int r = 0; r < 4; ++r) {
                    const int row = bm + wm + i * 16 + quad * 4 + r;
                    C[(size_t)row * ldc + col] = acc[i][j][r] + bv;
                }
        }
    }
}

// ---- qn2/kn2 = rowwise dot of WqkvT[j,:] and TQKT_b[j,:], j in [0,1536) ------
// qn2[b*768+j] = ||q col j||^2 (j<768);  kn2[b*768+(j-768)] = ||k col||^2.
__global__ __launch_bounds__(256)
void rownorm(const unsigned short* __restrict__ W, const unsigned short* __restrict__ T,
             float* __restrict__ qn2, float* __restrict__ kn2) {
    const int row = blockIdx.x * 4 + (threadIdx.x >> 6);   // 0..12287
    const int lane = threadIdx.x & 63;
    const int b = row / 1536, j = row % 1536;
    const unsigned short* wr = W + (size_t)j * 768;
    const unsigned short* tr = T + (size_t)b * 1179648 + (size_t)j * 768;
    float s = 0.f;
    {
        short8 a = *(const short8*)(wr + lane * 8);
        short8 c = *(const short8*)(tr + lane * 8);
        #pragma unroll
        for (int e = 0; e < 8; ++e) s += b2f((unsigned short)a[e]) * b2f((unsigned short)c[e]);
    }
    if (lane < 32) {
        short8 a = *(const short8*)(wr + 512 + lane * 8);
        short8 c = *(const short8*)(tr + 512 + lane * 8);
        #pragma unroll
        for (int e = 0; e < 8; ++e) s += b2f((unsigned short)a[e]) * b2f((unsigned short)c[e]);
    }
    #pragma unroll
    for (int o = 32; o; o >>= 1) s += __shfl_down(s, o);
    if (lane == 0) {
        if (j < 768) qn2[b * 768 + j] = s;
        else         kn2[b * 768 + j - 768] = s;
    }
}

// ---- softmax over q of logits = t*S/(|k||q|); writes block-diag attn^T -------
// Sfull_b[(64h+p)*768 + 64h+q] holds raw S_h[p,q].
// Writes BTattn_b[(64h+q)*768 + 64h+p] = attn_h[p,q] (rest pre-zeroed).
__global__ __launch_bounds__(64)
void softmax_attn(const float* __restrict__ S, const float* __restrict__ qn2,
                  const float* __restrict__ kn2, const float* __restrict__ temp,
                  unsigned short* __restrict__ BTat) {
    const int bh = blockIdx.x, b = bh / 12, h = bh % 12, p = threadIdx.x;
    const float t = temp[h];
    const float knv = fmaxf(sqrtf(kn2[b * 768 + h * 64 + p]), 1e-12f);
    const float* Sr = S + (size_t)b * 589824 + (size_t)(h * 64 + p) * 768 + h * 64;
    const float* qr = qn2 + b * 768 + h * 64;
    float l[64];
    float mx = -1e30f;
    #pragma unroll
    for (int q = 0; q < 64; ++q) {
        const float qnv = fmaxf(sqrtf(qr[q]), 1e-12f);
        l[q] = t * Sr[q] / (knv * qnv);
        mx = fmaxf(mx, l[q]);
    }
    float sum = 0.f;
    #pragma unroll
    for (int q = 0; q < 64; ++q) { l[q] = __expf(l[q] - mx); sum += l[q]; }
    const float inv = 1.0f / sum;
    unsigned short* At = BTat + (size_t)b * 589824 + (size_t)(h * 64) * 768 + h * 64 + p;
    #pragma unroll
    for (int q = 0; q < 64; ++q) At[(size_t)q * 768] = f2b(l[q] * inv);
}

extern "C" void kernel_launch(void* const* d_in, const int* in_sizes, int n_in,
                              void* d_out, int out_size, void* d_ws, size_t ws_size,
                              hipStream_t stream) {
    const float *x = nullptr, *Wqkv = nullptr, *temp = nullptr, *Wout = nullptr, *bout = nullptr;
    for (int i = 0; i < n_in; ++i) {
        switch (in_sizes[i]) {
            case 25165824: x    = (const float*)d_in[i]; break;  // 8*4096*768
            case 1769472:  Wqkv = (const float*)d_in[i]; break;  // 768*2304
            case 12:       temp = (const float*)d_in[i]; break;  // (1,12,1,1)
            case 589824:   Wout = (const float*)d_in[i]; break;  // 768*768
            case 768:      bout = (const float*)d_in[i]; break;  // (768,)
        }
    }
    float* out = (float*)d_out;  // (8,4096,768) fp32

    // ---------------- workspace layout (bytes) --------------------------------
    char* ws = (char*)d_ws;
    unsigned short* WqkvT = (unsigned short*)(ws + 0);          //  3,538,944  (2304x768)
    unsigned short* WoutT = (unsigned short*)(ws + 3538944);    //  1,179,648  (768x768)
    unsigned short* Wbf   = (unsigned short*)(ws + 4718592);    //  3,538,944  (768x2304)
    unsigned short* xb    = (unsigned short*)(ws + 8257536);    // 50,331,648  (32768x768)
    unsigned short* xT    = (unsigned short*)(ws + 58589184);   // 50,331,648  (768x32768), dead after G
    unsigned short* TQKT  = (unsigned short*)(ws + 58589184);   // 18,874,368  (8 x 1536x768) [aliases xT]
    float*          Sfull = (float*)         (ws + 77463552);   // 18,874,368  (8 x 768x768 f32) [aliases xT]
    float*          qn2   = (float*)         (ws + 96337920);   //     24,576
    float*          kn2   = (float*)         (ws + 96362496);   //     24,576
    unsigned short* G     = (unsigned short*)(ws + 108920832);  //  9,437,184  (8 x 768x768)
    unsigned short* BTat  = (unsigned short*)(ws + 118358016);  //  9,437,184  (8 x 768x768)
    unsigned short* W2    = (unsigned short*)(ws + 127795200);  //  9,437,184  (8 x 768x768)
    unsigned short* FT    = (unsigned short*)(ws + 137232384);  //  9,437,184  (8 x 768x768)
    (void)ws_size;  // requires ~147 MB; prior c=8 path proved >= 258 MB available

    // ---- weight prep ---------------------------------------------------------
    transpose_f32_bf16<<<dim3(2304 / 32, 768 / 32), 256, 0, stream>>>(Wqkv, WqkvT, 768, 2304);
    transpose_f32_bf16<<<dim3(768 / 32, 768 / 32), 256, 0, stream>>>(Wout, WoutT, 768, 768);
    cvt_f32_bf16<<<dim3(864), 256, 0, stream>>>(Wqkv, Wbf, 1769472LL);
    hipMemsetAsync(BTat, 0, 9437184, stream);

    // ---- x -> bf16 row-major + transposed ------------------------------------
    cvt_tr<<<dim3(24, 1024), 256, 0, stream>>>(x, xb, xT);

    // ---- G_b = x_b^T x_b  (768x768, K=4096), bf16 out ------------------------
    gemm_bt_g<0><<<dim3(6, 6, 8), 256, 0, stream>>>(
        xT, xT, G, nullptr, 4096, 32768, 32768, 768, 4096LL, 4096LL, 589824LL);

    // ---- TQKT_b = Wqk^T G_b  (1536x768, K=768), bf16 out ---------------------
    gemm_bt_g<0><<<dim3(6, 12, 8), 256, 0, stream>>>(
        WqkvT, G, TQKT, nullptr, 768, 768, 768, 768, 0LL, 589824LL, 1179648LL);

    // ---- qn2/kn2 = diag(W^T G W) via row dots --------------------------------
    rownorm<<<dim3(3072), 256, 0, stream>>>(WqkvT, TQKT, qn2, kn2);

    // ---- Sfull_b = Wk^T (G Wq)  (768x768, K=768), f32 out --------------------
    gemm_bt_g<1><<<dim3(6, 6, 8), 256, 0, stream>>>(
        WqkvT + 589824, TQKT, Sfull, nullptr, 768, 768, 768, 768, 0LL, 1179648LL, 589824LL);

    // ---- softmax -> block-diagonal attn^T (bf16) -----------------------------
    softmax_attn<<<dim3(96), 64, 0, stream>>>(Sfull, qn2, kn2, temp, BTat);

    // ---- W2_b = Wv @ blockdiag(attn)  (768x768, K=768), bf16 out -------------
    gemm_bt_g<0><<<dim3(6, 6, 8), 256, 0, stream>>>(
        Wbf + 1536, BTat, W2, nullptr, 768, 2304, 768, 768, 0LL, 589824LL, 589824LL);

    // ---- FT_b = (W2_b @ Wout)^T  (768x768, K=768), bf16 out ------------------
    gemm_bt_g<0><<<dim3(6, 6, 8), 256, 0, stream>>>(
        WoutT, W2, FT, nullptr, 768, 768, 768, 768, 0LL, 589824LL, 589824LL);

    // ---- out_b = x_b @ W3_b + bout  (4096x768, K=768), f32 + bias ------------
    gemm_bt_g<2><<<dim3(6, 32, 8), 256, 0, stream>>>(
        xb, FT, out, bout, 768, 768, 768, 768, 3145728LL, 589824LL, 3145728LL);
}

// Round 4
// 423.997 us; speedup vs baseline: 1.4273x; 1.0599x over previous
//
#include <hip/hip_runtime.h>

typedef __attribute__((ext_vector_type(8))) short short8;
typedef __attribute__((ext_vector_type(4))) float f32x4;

__device__ __forceinline__ float b2f(unsigned short u) {
    unsigned int i = ((unsigned int)u) << 16;
    return __builtin_bit_cast(float, i);
}
__device__ __forceinline__ unsigned short f2b(float f) {
    unsigned int u = __builtin_bit_cast(unsigned int, f);
    unsigned int r = (u + 0x7fffu + ((u >> 16) & 1u)) >> 16;
    return (unsigned short)r;
}

// async 16B global->LDS copy; lds base must be wave-uniform (HW adds lane*16B)
__device__ __forceinline__ void async16(unsigned short* lds, const unsigned short* g) {
    __builtin_amdgcn_global_load_lds(
        (const __attribute__((address_space(1))) unsigned int*)g,
        (__attribute__((address_space(3))) unsigned int*)lds,
        16, 0, 0);
}

// XCD-aware block swizzle; only applied when gridDim.y % 8 == 0 (bijective).
__device__ __forceinline__ void xcd_swizzle(int& bx, int& by) {
    if ((gridDim.y & 7) == 0) {
        const int nx = gridDim.x;
        const int rows_per_xcd = gridDim.y >> 3;
        const int flat = blockIdx.y * nx + blockIdx.x;
        const int xcd = flat & 7;
        const int i = flat >> 3;
        by = xcd * rows_per_xcd + i / nx;
        bx = i % nx;
    } else {
        bx = blockIdx.x; by = blockIdx.y;
    }
}

// ------------- fp32 -> bf16 bulk convert (8 elts/thread) ----------------------
__global__ __launch_bounds__(256)
void cvt_f32_bf16(const float* __restrict__ in, unsigned short* __restrict__ out,
                  long long n8) {
    const long long i = ((long long)blockIdx.x * 256 + threadIdx.x) * 8;
    if (i >= n8) return;
    f32x4 a = *(const f32x4*)(in + i);
    f32x4 b = *(const f32x4*)(in + i + 4);
    short8 o;
    #pragma unroll
    for (int j = 0; j < 4; ++j) { o[j] = (short)f2b(a[j]); o[j + 4] = (short)f2b(b[j]); }
    *(short8*)(out + i) = o;
}

// ------------- transpose + fp32->bf16 convert (weights) -----------------------
__global__ __launch_bounds__(256)
void transpose_f32_bf16(const float* __restrict__ in, unsigned short* __restrict__ out,
                        int R, int C) {
    __shared__ unsigned short t[32][33];
    const int r0 = blockIdx.y * 32, c0 = blockIdx.x * 32;
    const int tx = threadIdx.x & 31, ty = threadIdx.x >> 5;
    #pragma unroll
    for (int i = 0; i < 32; i += 8)
        t[ty + i][tx] = f2b(in[(size_t)(r0 + ty + i) * C + c0 + tx]);
    __syncthreads();
    #pragma unroll
    for (int i = 0; i < 32; i += 8)
        out[(size_t)(c0 + ty + i) * R + r0 + tx] = t[tx][ty + i];
}

// ------------- x: fused fp32->bf16 convert + transpose, 16B IO both sides -----
// in: (32768 x 768) fp32. rm: (32768 x 768) bf16. tm: (768 x 32768) bf16.
__global__ __launch_bounds__(256)
void cvt_tr64(const float* __restrict__ in, unsigned short* __restrict__ rm,
              unsigned short* __restrict__ tm) {
    __shared__ unsigned short T[64][72];
    const int c0 = blockIdx.x * 64, r0 = blockIdx.y * 64;
    const int tr = threadIdx.x >> 2, tc = (threadIdx.x & 3) * 16;
    {
        const float* src = in + (size_t)(r0 + tr) * 768 + c0 + tc;
        f32x4 a0 = *(const f32x4*)(src);
        f32x4 a1 = *(const f32x4*)(src + 4);
        f32x4 a2 = *(const f32x4*)(src + 8);
        f32x4 a3 = *(const f32x4*)(src + 12);
        short8 o0, o1;
        #pragma unroll
        for (int j = 0; j < 4; ++j) {
            o0[j] = (short)f2b(a0[j]); o0[j + 4] = (short)f2b(a1[j]);
            o1[j] = (short)f2b(a2[j]); o1[j + 4] = (short)f2b(a3[j]);
        }
        *(short8*)&T[tr][tc] = o0;
        *(short8*)&T[tr][tc + 8] = o1;
        unsigned short* d = rm + (size_t)(r0 + tr) * 768 + c0 + tc;
        *(short8*)(d) = o0;
        *(short8*)(d + 8) = o1;
    }
    __syncthreads();
    short8 s0, s1;
    #pragma unroll
    for (int e = 0; e < 8; ++e) {
        s0[e] = (short)T[tc + e][tr];
        s1[e] = (short)T[tc + 8 + e][tr];
    }
    unsigned short* d = tm + (size_t)(c0 + tr) * 32768 + r0 + tc;
    *(short8*)(d) = s0;
    *(short8*)(d + 8) = s1;
}

// =============================================================================
// Split-K Gram partials: Gp[z] = xT_b[:, s*1024 : +1024] self-product (bf16).
// z = b*4 + s. Grid (6, 6, 32). m97 structure, 128x128 tile, BK=32.
// =============================================================================
__global__ __launch_bounds__(256, 2)
void gram_split(const unsigned short* __restrict__ xT, unsigned short* __restrict__ Gp) {
    __shared__ unsigned short As[128 * 32];
    __shared__ unsigned short Bs[128 * 32];
    const int z = blockIdx.z, b = z >> 2, s = z & 3;
    const int tid  = threadIdx.x;
    const int wave = tid >> 6, lane = tid & 63;
    const int quad = lane >> 4, m16 = lane & 15;
    const int bm = blockIdx.y * 128, bn = blockIdx.x * 128;
    const int wm = (wave >> 1) * 64, wn = (wave & 1) * 64;
    const int srow = wave * 32 + (lane >> 2);
    const int scol = (lane & 3) * 8;
    const unsigned short* base = xT + (size_t)b * 4096 + s * 1024 + scol;
    const unsigned short* Ag = base + (size_t)(bm + srow) * 32768;
    const unsigned short* Bg = base + (size_t)(bn + srow) * 32768;
    unsigned short* Asw = &As[(wave * 32) * 32];
    unsigned short* Bsw = &Bs[(wave * 32) * 32];
    f32x4 acc[4][4] = {};

    for (int k0 = 0; k0 < 1024; k0 += 32) {
        __syncthreads();
        async16(Asw,           Ag + k0);
        async16(Asw + 16 * 32, Ag + k0 + (size_t)16 * 32768);
        async16(Bsw,           Bg + k0);
        async16(Bsw + 16 * 32, Bg + k0 + (size_t)16 * 32768);
        __syncthreads();
        short8 af[4], bfr[4];
        #pragma unroll
        for (int i = 0; i < 4; ++i)
            af[i] = *(const short8*)&As[(wm + i * 16 + m16) * 32 + quad * 8];
        #pragma unroll
        for (int j = 0; j < 4; ++j)
            bfr[j] = *(const short8*)&Bs[(wn + j * 16 + m16) * 32 + quad * 8];
        #pragma unroll
        for (int i = 0; i < 4; ++i)
            #pragma unroll
            for (int j = 0; j < 4; ++j)
                acc[i][j] = __builtin_amdgcn_mfma_f32_16x16x32_bf16(af[i], bfr[j], acc[i][j], 0, 0, 0);
    }
    unsigned short* C = Gp + (size_t)z * 589824;
    #pragma unroll
    for (int j = 0; j < 4; ++j) {
        const int col = bn + wn + j * 16 + m16;
        #pragma unroll
        for (int i = 0; i < 4; ++i)
            #pragma unroll
            for (int r = 0; r < 4; ++r) {
                const int row = bm + wm + i * 16 + quad * 4 + r;
                C[(size_t)row * 768 + col] = f2b(acc[i][j][r]);
            }
    }
}

// ---- G[b] = sum_s Gp[b*4+s] (bf16 -> f32 sum -> bf16), 8 elts/thread ---------
__global__ __launch_bounds__(256)
void g_reduce(const unsigned short* __restrict__ Gp, unsigned short* __restrict__ G) {
    const int b = blockIdx.y;
    const int off = blockIdx.x * 2048 + threadIdx.x * 8;
    const unsigned short* p = Gp + (size_t)b * 4 * 589824 + off;
    float s[8] = {};
    #pragma unroll
    for (int sp = 0; sp < 4; ++sp) {
        short8 v = *(const short8*)(p + (size_t)sp * 589824);
        #pragma unroll
        for (int e = 0; e < 8; ++e) s[e] += b2f((unsigned short)v[e]);
    }
    short8 o;
    #pragma unroll
    for (int e = 0; e < 8; ++e) o[e] = (short)f2b(s[e]);
    *(short8*)(G + (size_t)b * 589824 + off) = o;
}

// =============================================================================
// Generalized m97-style GEMM: C = A @ BT^T (bf16 in), 128x128 tile, BK=32,
// batched over blockIdx.z. OM: 0 = bf16 out, 2 = f32 out + bias[col].
// =============================================================================
template<int OM>
__global__ __launch_bounds__(256, 2)
void gemm_bt_g(const unsigned short* A, const unsigned short* BT,
               void* __restrict__ Cv, const float* __restrict__ bias,
               int K, int lda, int ldb, int ldc,
               long long sA, long long sB, long long sC) {
    __shared__ unsigned short As[128 * 32];
    __shared__ unsigned short Bs[128 * 32];
    const int z = blockIdx.z;
    A  += (size_t)z * sA;
    BT += (size_t)z * sB;
    int bxi, byi;
    xcd_swizzle(bxi, byi);
    const int tid  = threadIdx.x;
    const int wave = tid >> 6, lane = tid & 63;
    const int quad = lane >> 4, m16 = lane & 15;
    const int bm = byi * 128, bn = bxi * 128;
    const int wm = (wave >> 1) * 64, wn = (wave & 1) * 64;
    const int srow = wave * 32 + (lane >> 2);
    const int scol = (lane & 3) * 8;
    const unsigned short* Ag = A + (size_t)(bm + srow) * lda + scol;
    const unsigned short* Bg = BT + (size_t)(bn + srow) * ldb + scol;
    unsigned short* Asw = &As[(wave * 32) * 32];
    unsigned short* Bsw = &Bs[(wave * 32) * 32];
    f32x4 acc[4][4] = {};

    for (int k0 = 0; k0 < K; k0 += 32) {
        __syncthreads();
        async16(Asw,           Ag + k0);
        async16(Asw + 16 * 32, Ag + k0 + (size_t)16 * lda);
        async16(Bsw,           Bg + k0);
        async16(Bsw + 16 * 32, Bg + k0 + (size_t)16 * ldb);
        __syncthreads();
        short8 af[4], bfr[4];
        #pragma unroll
        for (int i = 0; i < 4; ++i)
            af[i] = *(const short8*)&As[(wm + i * 16 + m16) * 32 + quad * 8];
        #pragma unroll
        for (int j = 0; j < 4; ++j)
            bfr[j] = *(const short8*)&Bs[(wn + j * 16 + m16) * 32 + quad * 8];
        #pragma unroll
        for (int i = 0; i < 4; ++i)
            #pragma unroll
            for (int j = 0; j < 4; ++j)
                acc[i][j] = __builtin_amdgcn_mfma_f32_16x16x32_bf16(af[i], bfr[j], acc[i][j], 0, 0, 0);
    }

    if constexpr (OM == 0) {
        unsigned short* C = (unsigned short*)Cv + (size_t)z * sC;
        #pragma unroll
        for (int j = 0; j < 4; ++j) {
            const int col = bn + wn + j * 16 + m16;
            #pragma unroll
            for (int i = 0; i < 4; ++i)
                #pragma unroll
                for (int r = 0; r < 4; ++r) {
                    const int row = bm + wm + i * 16 + quad * 4 + r;
                    C[(size_t)row * ldc + col] = f2b(acc[i][j][r]);
                }
        }
    } else {
        float* C = (float*)Cv + (size_t)z * sC;
        #pragma unroll
        for (int j = 0; j < 4; ++j) {
            const int col = bn + wn + j * 16 + m16;
            const float bv = bias[col];
            #pragma unroll
            for (int i = 0; i < 4; ++i)
                #pragma unroll
                for (int r = 0; r < 4; ++r) {
                    const int row = bm + wm + i * 16 + quad * 4 + r;
                    C[(size_t)row * ldc + col] = acc[i][j][r] + bv;
                }
        }
    }
}

// ---- qn2/kn2 = rowwise dot of WqkvT[j,:] and TQKT_b[j,:], j in [0,1536) ------
__global__ __launch_bounds__(256)
void rownorm(const unsigned short* __restrict__ W, const unsigned short* __restrict__ T,
             float* __restrict__ qn2, float* __restrict__ kn2) {
    const int row = blockIdx.x * 4 + (threadIdx.x >> 6);   // 0..12287
    const int lane = threadIdx.x & 63;
    const int b = row / 1536, j = row % 1536;
    const unsigned short* wr = W + (size_t)j * 768;
    const unsigned short* tr = T + (size_t)b * 1179648 + (size_t)j * 768;
    float s = 0.f;
    {
        short8 a = *(const short8*)(wr + lane * 8);
        short8 c = *(const short8*)(tr + lane * 8);
        #pragma unroll
        for (int e = 0; e < 8; ++e) s += b2f((unsigned short)a[e]) * b2f((unsigned short)c[e]);
    }
    if (lane < 32) {
        short8 a = *(const short8*)(wr + 512 + lane * 8);
        short8 c = *(const short8*)(tr + 512 + lane * 8);
        #pragma unroll
        for (int e = 0; e < 8; ++e) s += b2f((unsigned short)a[e]) * b2f((unsigned short)c[e]);
    }
    #pragma unroll
    for (int o = 32; o; o >>= 1) s += __shfl_down(s, o);
    if (lane == 0) {
        if (j < 768) qn2[b * 768 + j] = s;
        else         kn2[b * 768 + j - 768] = s;
    }
}

// =============================================================================
// Fused per-(b,h): S = Wk_h^T (G Wq_h) via MFMA, softmax over q, then
// W2_h = Wv_h @ attn_h (768x64). Replaces Sfull GEMM + softmax + dense W2 GEMM.
// Grid 96 blocks x 256 threads.
// =============================================================================
__global__ __launch_bounds__(256)
void head_fused(const unsigned short* __restrict__ WqkvT,
                const unsigned short* __restrict__ TQKT,
                const unsigned short* __restrict__ Wbf,
                const float* __restrict__ qn2, const float* __restrict__ kn2,
                const float* __restrict__ temp, unsigned short* __restrict__ W2) {
    const int bh = blockIdx.x, b = bh / 12, h = bh % 12;
    __shared__ unsigned short As[64][72], Bs[64][72], At[64][72];
    __shared__ float Sf[64][65];
    __shared__ float qinv[64], kinv[64], red[64][4], red2[64][4];
    const int tid = threadIdx.x;
    const int wave = tid >> 6, lane = tid & 63;
    const int quad = lane >> 4, m16 = lane & 15;
    const int wr = wave >> 1, wc = wave & 1;

    if (tid < 64) {
        qinv[tid] = 1.0f / fmaxf(sqrtf(qn2[b * 768 + h * 64 + tid]), 1e-12f);
        kinv[tid] = 1.0f / fmaxf(sqrtf(kn2[b * 768 + h * 64 + tid]), 1e-12f);
    }

    // ---- phase A: S (64x64) = A . B^T, A rows = Wk cols, B rows = (G Wq)^T ---
    f32x4 sacc[2][2] = {};
    const int srow = tid >> 3, scol8 = (tid & 7) * 8;
    const unsigned short* Arow = WqkvT + (size_t)(768 + h * 64) * 768;
    const unsigned short* Brow = TQKT + (size_t)(b * 1536 + h * 64) * 768;
    for (int k0 = 0; k0 < 768; k0 += 64) {
        __syncthreads();
        *(short8*)&As[srow][scol8]      = *(const short8*)(Arow + (size_t)srow * 768 + k0 + scol8);
        *(short8*)&As[srow + 32][scol8] = *(const short8*)(Arow + (size_t)(srow + 32) * 768 + k0 + scol8);
        *(short8*)&Bs[srow][scol8]      = *(const short8*)(Brow + (size_t)srow * 768 + k0 + scol8);
        *(short8*)&Bs[srow + 32][scol8] = *(const short8*)(Brow + (size_t)(srow + 32) * 768 + k0 + scol8);
        __syncthreads();
        #pragma unroll
        for (int ks = 0; ks < 2; ++ks) {
            short8 af[2], bv[2];
            af[0] = *(const short8*)&As[wr * 32 + m16][ks * 32 + quad * 8];
            af[1] = *(const short8*)&As[wr * 32 + 16 + m16][ks * 32 + quad * 8];
            bv[0] = *(const short8*)&Bs[wc * 32 + m16][ks * 32 + quad * 8];
            bv[1] = *(const short8*)&Bs[wc * 32 + 16 + m16][ks * 32 + quad * 8];
            #pragma unroll
            for (int i = 0; i < 2; ++i)
                #pragma unroll
                for (int j = 0; j < 2; ++j)
                    sacc[i][j] = __builtin_amdgcn_mfma_f32_16x16x32_bf16(af[i], bv[j], sacc[i][j], 0, 0, 0);
        }
    }
    __syncthreads();
    #pragma unroll
    for (int i = 0; i < 2; ++i)
        #pragma unroll
        for (int j = 0; j < 2; ++j)
            #pragma unroll
            for (int r = 0; r < 4; ++r)
                Sf[wr * 32 + i * 16 + quad * 4 + r][wc * 32 + j * 16 + m16] = sacc[i][j][r];
    __syncthreads();

    // ---- phase B: softmax over q for each row p (4 lane-groups of 16 q) ------
    const float tt = temp[h];
    const int p = tid & 63, g = tid >> 6;
    float l[16], mx = -1e30f;
    const float kvp = tt * kinv[p];
    #pragma unroll
    for (int e = 0; e < 16; ++e) {
        l[e] = kvp * Sf[p][g * 16 + e] * qinv[g * 16 + e];
        mx = fmaxf(mx, l[e]);
    }
    red[p][g] = mx;
    __syncthreads();
    mx = fmaxf(fmaxf(red[p][0], red[p][1]), fmaxf(red[p][2], red[p][3]));
    float sum = 0.f;
    #pragma unroll
    for (int e = 0; e < 16; ++e) { l[e] = __expf(l[e] - mx); sum += l[e]; }
    red2[p][g] = sum;
    __syncthreads();
    sum = red2[p][0] + red2[p][1] + red2[p][2] + red2[p][3];
    const float inv = 1.0f / sum;
    #pragma unroll
    for (int e = 0; e < 16; ++e) At[g * 16 + e][p] = f2b(l[e] * inv);
    __syncthreads();

    // ---- phase C: W2_h (768x64) = Wv_h @ attn; A frags direct from global ----
    const unsigned short* Wv = Wbf + 1536 + h * 64;
    unsigned short* W2b = W2 + (size_t)b * 589824 + h * 64;
    #pragma unroll
    for (int pass = 0; pass < 3; ++pass) {
        const int rb = wave * 192 + pass * 64;
        f32x4 wacc[4][4] = {};
        #pragma unroll
        for (int ks = 0; ks < 2; ++ks) {
            short8 av[4], bv[4];
            #pragma unroll
            for (int i = 0; i < 4; ++i)
                av[i] = *(const short8*)(Wv + (size_t)(rb + i * 16 + m16) * 2304 + ks * 32 + quad * 8);
            #pragma unroll
            for (int j = 0; j < 4; ++j)
                bv[j] = *(const short8*)&At[j * 16 + m16][ks * 32 + quad * 8];
            #pragma unroll
            for (int i = 0; i < 4; ++i)
                #pragma unroll
                for (int j = 0; j < 4; ++j)
                    wacc[i][j] = __builtin_amdgcn_mfma_f32_16x16x32_bf16(av[i], bv[j], wacc[i][j], 0, 0, 0);
        }
        #pragma unroll
        for (int j = 0; j < 4; ++j)
            #pragma unroll
            for (int i = 0; i < 4; ++i)
                #pragma unroll
                for (int r = 0; r < 4; ++r)
                    W2b[(size_t)(rb + i * 16 + quad * 4 + r) * 768 + j * 16 + m16] = f2b(wacc[i][j][r]);
    }
}

extern "C" void kernel_launch(void* const* d_in, const int* in_sizes, int n_in,
                              void* d_out, int out_size, void* d_ws, size_t ws_size,
                              hipStream_t stream) {
    const float *x = nullptr, *Wqkv = nullptr, *temp = nullptr, *Wout = nullptr, *bout = nullptr;
    for (int i = 0; i < n_in; ++i) {
        switch (in_sizes[i]) {
            case 25165824: x    = (const float*)d_in[i]; break;  // 8*4096*768
            case 1769472:  Wqkv = (const float*)d_in[i]; break;  // 768*2304
            case 12:       temp = (const float*)d_in[i]; break;  // (1,12,1,1)
            case 589824:   Wout = (const float*)d_in[i]; break;  // 768*768
            case 768:      bout = (const float*)d_in[i]; break;  // (768,)
        }
    }
    float* out = (float*)d_out;  // (8,4096,768) fp32

    // ---------------- workspace layout (bytes, peak 146.67 MB) ----------------
    char* ws = (char*)d_ws;
    unsigned short* WqkvT = (unsigned short*)(ws + 0);          //  3,538,944 (2304x768)
    unsigned short* WoutT = (unsigned short*)(ws + 3538944);    //  1,179,648 (768x768)
    unsigned short* Wbf   = (unsigned short*)(ws + 4718592);    //  3,538,944 (768x2304)
    unsigned short* xb    = (unsigned short*)(ws + 8257536);    // 50,331,648 (32768x768)
    unsigned short* xT    = (unsigned short*)(ws + 58589184);   // 50,331,648 (768x32768); dead after gram_split
    unsigned short* G     = (unsigned short*)(ws + 58589184);   //  9,437,184 (8x768x768) [aliases dead xT]
    unsigned short* TQKT  = (unsigned short*)(ws + 68026368);   // 18,874,368 (8x1536x768) [in dead xT]
    float*          qn2   = (float*)         (ws + 86900736);   //     24,576
    float*          kn2   = (float*)         (ws + 86925312);   //     24,576
    unsigned short* W2    = (unsigned short*)(ws + 86949888);   //  9,437,184 (8x768x768)
    unsigned short* FT    = (unsigned short*)(ws + 96387072);   //  9,437,184 (8x768x768)
    unsigned short* Gp    = (unsigned short*)(ws + 108920832);  // 37,748,736 (32x768x768 bf16 partials)
    (void)ws_size;  // peak 146,669,568 B == footprint proven by prior rounds

    // ---- weight prep ---------------------------------------------------------
    transpose_f32_bf16<<<dim3(72, 24), 256, 0, stream>>>(Wqkv, WqkvT, 768, 2304);
    transpose_f32_bf16<<<dim3(24, 24), 256, 0, stream>>>(Wout, WoutT, 768, 768);
    cvt_f32_bf16<<<dim3(864), 256, 0, stream>>>(Wqkv, Wbf, 1769472LL);

    // ---- x -> bf16 row-major + transposed (vectorized both sides) ------------
    cvt_tr64<<<dim3(12, 512), 256, 0, stream>>>(x, xb, xT);

    // ---- G_b = x_b^T x_b via split-K=4 partials + reduce ---------------------
    gram_split<<<dim3(6, 6, 32), 256, 0, stream>>>(xT, Gp);
    g_reduce<<<dim3(288, 8), 256, 0, stream>>>(Gp, G);

    // ---- TQKT_b = Wqk^T G_b  (1536x768, K=768) -------------------------------
    gemm_bt_g<0><<<dim3(6, 12, 8), 256, 0, stream>>>(
        WqkvT, G, TQKT, nullptr, 768, 768, 768, 768, 0LL, 589824LL, 1179648LL);

    // ---- qn2/kn2 = diag(W^T G W) ---------------------------------------------
    rownorm<<<dim3(3072), 256, 0, stream>>>(WqkvT, TQKT, qn2, kn2);

    // ---- fused: S + softmax + W2 (block-diagonal) per (b,h) ------------------
    head_fused<<<dim3(96), 256, 0, stream>>>(WqkvT, TQKT, Wbf, qn2, kn2, temp, W2);

    // ---- FT_b = (W2_b @ Wout)^T  (768x768, K=768) ----------------------------
    gemm_bt_g<0><<<dim3(6, 6, 8), 256, 0, stream>>>(
        WoutT, W2, FT, nullptr, 768, 768, 768, 768, 0LL, 589824LL, 589824LL);

    // ---- out_b = x_b @ W3_b + bout  (4096x768, K=768), f32 + bias ------------
    gemm_bt_g<2><<<dim3(6, 32, 8), 256, 0, stream>>>(
        xb, FT, out, bout, 768, 768, 768, 768, 3145728LL, 589824LL, 3145728LL);
}